// Round 1
// baseline (53.610 us; speedup 1.0000x reference)
//
#include <hip/hip_runtime.h>
#include <hip/hip_bf16.h>

typedef __attribute__((ext_vector_type(8))) short bf16x8_t;
typedef __attribute__((ext_vector_type(4))) float f32x4_t;

#define NB 8
#define NO 2048
#define NQ 2048
#define ND 128

__device__ __forceinline__ float fast_exp2(float x){
#if __has_builtin(__builtin_amdgcn_exp2f)
  return __builtin_amdgcn_exp2f(x);
#else
  return exp2f(x);
#endif
}

// round-to-nearest-even f32 -> bf16 bits (finite inputs only)
__device__ __forceinline__ short f2bf(float f){
  unsigned u = __float_as_uint(f);
  unsigned r = (u + 0x7fffu + ((u >> 16) & 1u)) >> 16;
  return (short)(unsigned short)r;
}

// ---------------- prep: Et[b][d][o] = bf16(obs_emb[b][o][d]);  Wbf = bf16(W_proj)
__global__ __launch_bounds__(256) void prep_kernel(
    const float* __restrict__ obs_emb, const float* __restrict__ W_proj,
    short* __restrict__ Et, short* __restrict__ Wbf)
{
  const int blk = blockIdx.x;
  const int tid = threadIdx.x;
  if (blk < NB * (NO / 64)) {
    __shared__ short tileT[ND][72];          // pad to 72 shorts: 144B rows, 16B aligned
    const int b  = blk >> 5;                 // 32 blocks per batch (NO/64)
    const int o0 = (blk & 31) * 64;
    #pragma unroll
    for (int i = 0; i < 8; ++i) {
      int c  = i * 256 + tid;                // 0..2047 float4-chunks of 64x128 tile
      int ol = c >> 5;                       // 0..63
      int dc = c & 31;                       // 0..31
      const float4 v = *reinterpret_cast<const float4*>(
          obs_emb + ((size_t)(b * NO + o0 + ol)) * ND + dc * 4);
      tileT[dc*4+0][ol] = f2bf(v.x);
      tileT[dc*4+1][ol] = f2bf(v.y);
      tileT[dc*4+2][ol] = f2bf(v.z);
      tileT[dc*4+3][ol] = f2bf(v.w);
    }
    __syncthreads();
    const int d = tid >> 1, h = tid & 1;     // each thread: 64B of one d-row
    const int4* src = reinterpret_cast<const int4*>(&tileT[d][h * 32]);
    int4* dst = reinterpret_cast<int4*>(Et + ((size_t)(b * ND + d)) * NO + o0 + h * 32);
    dst[0] = src[0]; dst[1] = src[1]; dst[2] = src[2]; dst[3] = src[3];
  } else {
    // W conversion: 128x128 f32 -> bf16, row-major unchanged
    #pragma unroll
    for (int i = 0; i < 16; ++i) {
      int idx = i * 256 + tid;               // float4 index 0..4095
      float4 v = reinterpret_cast<const float4*>(W_proj)[idx];
      union { int2 i2; __hip_bfloat162 h[2]; } u;
      u.h[0] = __float22bfloat162_rn(make_float2(v.x, v.y));
      u.h[1] = __float22bfloat162_rn(make_float2(v.z, v.w));
      reinterpret_cast<int2*>(Wbf)[idx] = u.i2;
    }
  }
}

// ---------------- main fused kernel
// grid: 512 blocks = 8 batches x 64 q-tiles(32 rows). 256 thr = 4 waves.
// wave(qi,dh): q-rows [q0+qi*16, +16), d/e-cols [dh*64, +64)
__global__ __launch_bounds__(256, 2) void agg_kernel(
    const float* __restrict__ obs_times, const float* __restrict__ query_times,
    const float* __restrict__ obs_mask, const float* __restrict__ log_sigma,
    const short* __restrict__ Et, const short* __restrict__ Wbf,
    const float* __restrict__ b_proj, float* __restrict__ out)
{
  __shared__ float2 tm_s[NO];                   // (Co, Bo') per o: 16 KB
  __shared__ __align__(16) char regR[8704];     // Elds[128][32] (8KB)  UNION  qe[32][136]
  short* Elds = reinterpret_cast<short*>(regR);
  short* qe   = reinterpret_cast<short*>(regR);

  const int tid  = threadIdx.x;
  const int lane = tid & 63;
  const int wave = tid >> 6;
  const int qi  = wave & 1;
  const int dh  = wave >> 1;
  const int row = lane & 15;
  const int g   = lane >> 4;

  const int b  = blockIdx.x >> 6;               // 64 q-tiles per batch
  const int q0 = (blockIdx.x & 63) * 32;

  const float ls    = log_sigma[0];
  const float kcoef = 0.72134752f * __expf(-2.0f * ls);  // 0.5*log2(e)/sigma^2

  // stage per-o weight coefficients: arg = Aq + Co*tq + Bo', Bo' folds log2(mask)
  for (int o = tid; o < NO; o += 256) {
    float to = obs_times[b * NO + o];
    float m  = obs_mask[b * NO + o];
    float lm = __log2f(m);                      // mask=0 -> -inf -> weight 0
    tm_s[o] = make_float2(2.0f * kcoef * to, fmaf(-kcoef * to, to, lm));
  }

  const float tq = query_times[b * NQ + q0 + qi * 16 + row];
  const float Aq = -kcoef * tq * tq;

  f32x4_t acc[4];
  #pragma unroll
  for (int nt = 0; nt < 4; ++nt) acc[nt] = f32x4_t{0.f, 0.f, 0.f, 0.f};
  float wsum = 0.f;

  const short* EtB = Et + (size_t)b * ND * NO;

  for (int ko = 0; ko < NO; ko += 32) {
    __syncthreads();                            // prev tile consumed / tm ready (iter 0)
    #pragma unroll
    for (int j = 0; j < 2; ++j) {
      int c = tid + 256 * j;                    // 16B chunk id 0..511 (lane-contig LDS writes)
      int d = c >> 2, s = c & 3;
      int4 v = *reinterpret_cast<const int4*>(EtB + (size_t)d * NO + ko + s * 8);
      *reinterpret_cast<int4*>(Elds + c * 8) = v;
    }
    __syncthreads();

    const float4* tmf = reinterpret_cast<const float4*>(tm_s + ko) + g * 4;
    float4 p0 = tmf[0], p1 = tmf[1], p2 = tmf[2], p3 = tmf[3];
    float w0 = fast_exp2(Aq + fmaf(p0.x, tq, p0.y));
    float w1 = fast_exp2(Aq + fmaf(p0.z, tq, p0.w));
    float w2 = fast_exp2(Aq + fmaf(p1.x, tq, p1.y));
    float w3 = fast_exp2(Aq + fmaf(p1.z, tq, p1.w));
    float w4 = fast_exp2(Aq + fmaf(p2.x, tq, p2.y));
    float w5 = fast_exp2(Aq + fmaf(p2.z, tq, p2.w));
    float w6 = fast_exp2(Aq + fmaf(p3.x, tq, p3.y));
    float w7 = fast_exp2(Aq + fmaf(p3.z, tq, p3.w));
    wsum += ((w0 + w1) + (w2 + w3)) + ((w4 + w5) + (w6 + w7));

    union { bf16x8_t v; __hip_bfloat162 h[4]; } af;
    af.h[0] = __float22bfloat162_rn(make_float2(w0, w1));
    af.h[1] = __float22bfloat162_rn(make_float2(w2, w3));
    af.h[2] = __float22bfloat162_rn(make_float2(w4, w5));
    af.h[3] = __float22bfloat162_rn(make_float2(w6, w7));

    #pragma unroll
    for (int nt = 0; nt < 4; ++nt) {
      bf16x8_t bfrag = *reinterpret_cast<const bf16x8_t*>(
          Elds + (dh * 64 + nt * 16 + row) * 32 + g * 8);
      acc[nt] = __builtin_amdgcn_mfma_f32_16x16x32_bf16(af.v, bfrag, acc[nt], 0, 0, 0);
    }
  }

  // full per-row weight sum (row = lane&15)
  wsum += __shfl_xor(wsum, 16);
  wsum += __shfl_xor(wsum, 32);

  __syncthreads();                              // everyone done with Elds
  // normalize + transpose into qe (bf16) for the projection GEMM
  #pragma unroll
  for (int r = 0; r < 4; ++r) {
    float ws  = __shfl(wsum, g * 4 + r);        // lanes 0..15 hold rows 0..15
    float inv = 1.0f / fmaxf(ws, 1e-8f);
    #pragma unroll
    for (int nt = 0; nt < 4; ++nt) {
      qe[(qi * 16 + g * 4 + r) * 136 + dh * 64 + nt * 16 + row] = f2bf(acc[nt][r] * inv);
    }
  }
  __syncthreads();

  // projection: out[q][e] = sum_d qe[q][d] * W[e][d] + b[e]
  f32x4_t pacc[4];
  #pragma unroll
  for (int nt = 0; nt < 4; ++nt) pacc[nt] = f32x4_t{0.f, 0.f, 0.f, 0.f};
  #pragma unroll
  for (int ks = 0; ks < 4; ++ks) {
    bf16x8_t aq = *reinterpret_cast<const bf16x8_t*>(
        qe + (qi * 16 + row) * 136 + ks * 32 + g * 8);
    #pragma unroll
    for (int nt = 0; nt < 4; ++nt) {
      bf16x8_t bw = *reinterpret_cast<const bf16x8_t*>(
          Wbf + (dh * 64 + nt * 16 + row) * 128 + ks * 32 + g * 8);
      pacc[nt] = __builtin_amdgcn_mfma_f32_16x16x32_bf16(aq, bw, pacc[nt], 0, 0, 0);
    }
  }
  #pragma unroll
  for (int nt = 0; nt < 4; ++nt) {
    int e = dh * 64 + nt * 16 + row;
    float bias = b_proj[e];
    #pragma unroll
    for (int r = 0; r < 4; ++r) {
      int q = q0 + qi * 16 + g * 4 + r;
      out[((size_t)(b * NQ + q)) * ND + e] = pacc[nt][r] + bias;
    }
  }
}

extern "C" void kernel_launch(void* const* d_in, const int* in_sizes, int n_in,
                              void* d_out, int out_size, void* d_ws, size_t ws_size,
                              hipStream_t stream) {
  const float* obs_emb     = (const float*)d_in[0];
  const float* obs_times   = (const float*)d_in[1];
  const float* query_times = (const float*)d_in[2];
  const float* obs_mask    = (const float*)d_in[3];
  const float* log_sigma   = (const float*)d_in[4];
  const float* W_proj      = (const float*)d_in[5];
  const float* b_proj      = (const float*)d_in[6];
  float* out = (float*)d_out;

  short* Et  = (short*)d_ws;                         // 8*128*2048 bf16 = 4 MB
  short* Wbf = Et + (size_t)NB * ND * NO;            // 128*128 bf16 = 32 KB

  prep_kernel<<<NB * (NO / 64) + 1, 256, 0, stream>>>(obs_emb, W_proj, Et, Wbf);
  agg_kernel<<<NB * (NQ / 32), 256, 0, stream>>>(obs_times, query_times, obs_mask,
                                                 log_sigma, Et, Wbf, b_proj, out);
}

// Round 2
// 51.195 us; speedup vs baseline: 1.0472x; 1.0472x over previous
//
#include <hip/hip_runtime.h>
#include <hip/hip_bf16.h>

typedef __attribute__((ext_vector_type(8))) short bf16x8_t;
typedef __attribute__((ext_vector_type(4))) float f32x4_t;

#define NB 8
#define NO 2048
#define NQ 2048
#define ND 128

__device__ __forceinline__ float fast_exp2(float x){
#if __has_builtin(__builtin_amdgcn_exp2f)
  return __builtin_amdgcn_exp2f(x);
#else
  return exp2f(x);
#endif
}

// round-to-nearest-even f32 -> bf16 bits (finite inputs only)
__device__ __forceinline__ short f2bf(float f){
  unsigned u = __float_as_uint(f);
  unsigned r = (u + 0x7fffu + ((u >> 16) & 1u)) >> 16;
  return (short)(unsigned short)r;
}

#define GLOAD_LDS16(gsrc, ldst)                                                             \
  __builtin_amdgcn_global_load_lds((const __attribute__((address_space(1))) unsigned*)(gsrc), \
                                   (__attribute__((address_space(3))) unsigned*)(ldst), 16, 0, 0)

// ---------------- prep: Et[b][d][o] = bf16(obs_emb[b][o][d]);  Wbf = bf16(W_proj)
// LDS transpose tile swizzled with key=(d>>2)&7 on the o-16B-slot bits (bank-conflict fix).
__global__ __launch_bounds__(256) void prep_kernel(
    const float* __restrict__ obs_emb, const float* __restrict__ W_proj,
    short* __restrict__ Et, short* __restrict__ Wbf)
{
  const int blk = blockIdx.x;
  const int tid = threadIdx.x;
  if (blk < NB * (NO / 64)) {
    __shared__ __align__(16) short tileT[128 * 64];   // [d][swizzled o], 16 KB
    const int b  = blk >> 5;
    const int o0 = (blk & 31) * 64;
    #pragma unroll
    for (int i = 0; i < 8; ++i) {
      int c  = i * 256 + tid;                // 0..2047 float4-chunks of 64x128 tile
      int ol = c >> 5;                       // o 0..63
      int dc = c & 31;                       // d-quad 0..31
      union { float4 v4; float f[4]; } u;
      u.v4 = *reinterpret_cast<const float4*>(
          obs_emb + ((size_t)(b * NO + o0 + ol)) * ND + dc * 4);
      int j = ol >> 3, oin = ol & 7;         // 16B slot j (0..7), element within
      #pragma unroll
      for (int q = 0; q < 4; ++q) {
        int d = dc * 4 + q;
        tileT[d * 64 + ((j ^ ((d >> 2) & 7)) << 3) + oin] = f2bf(u.f[q]);
      }
    }
    __syncthreads();
    // write-out: thread owns 64B of one d-row -> single 64B line in L2
    const int d = tid >> 1, h = tid & 1;
    const int key = (d >> 2) & 7;
    short* dstRow = Et + ((size_t)(b * ND + d)) * NO + o0;
    #pragma unroll
    for (int k = 0; k < 4; ++k) {
      int j = h * 4 + k;
      *reinterpret_cast<int4*>(dstRow + j * 8) =
          *reinterpret_cast<const int4*>(tileT + d * 64 + ((j ^ key) << 3));
    }
  } else {
    // W conversion: 128x128 f32 -> bf16, row-major unchanged
    #pragma unroll
    for (int i = 0; i < 16; ++i) {
      int idx = i * 256 + tid;               // float4 index 0..4095
      float4 v = reinterpret_cast<const float4*>(W_proj)[idx];
      union { int2 i2; __hip_bfloat162 h[2]; } u;
      u.h[0] = __float22bfloat162_rn(make_float2(v.x, v.y));
      u.h[1] = __float22bfloat162_rn(make_float2(v.z, v.w));
      reinterpret_cast<int2*>(Wbf)[idx] = u.i2;
    }
  }
}

// ---------------- main fused kernel
// grid: 256 blocks = 8 batches x 32 q-tiles(64 rows); b = blockIdx&7 -> XCD-aligned.
// 512 thr = 8 waves: qi = wave&3 (16 q rows), dh = wave>>2 (64 d cols).
// K-loop: 2-phase double-buffered global_load_lds (1 barrier / 32-o step).
__global__ __launch_bounds__(512, 2) void agg_kernel(
    const float* __restrict__ obs_times, const float* __restrict__ query_times,
    const float* __restrict__ obs_mask, const float* __restrict__ log_sigma,
    const short* __restrict__ Et, const short* __restrict__ Wbf,
    const float* __restrict__ b_proj, float* __restrict__ out)
{
  __shared__ __align__(16) char smem[16384 + 16384];  // tm (16KB) + Elds dbuf (2x8KB)
  float2* tm_s = reinterpret_cast<float2*>(smem);
  short*  Elds = reinterpret_cast<short*>(smem + 16384);
  short*  qe   = reinterpret_cast<short*>(smem);      // epilogue overlay [64][136]

  const int tid  = threadIdx.x;
  const int lane = tid & 63;
  const int wave = tid >> 6;
  const int qi  = wave & 3;
  const int dh  = wave >> 2;
  const int row = lane & 15;
  const int g   = lane >> 4;

  const int b  = blockIdx.x & 7;             // XCD-aligned batch
  const int q0 = (blockIdx.x >> 3) * 64;

  const float ls    = log_sigma[0];
  const float kcoef = 0.72134752f * __expf(-2.0f * ls);  // 0.5*log2(e)/sigma^2

  // stage per-o weight coefficients: arg = Aq + Co*tq + Bo'; Bo' folds log2(mask)
  for (int o = tid; o < NO; o += 512) {
    float to = obs_times[b * NO + o];
    float m  = obs_mask[b * NO + o];
    float lm = __log2f(m);                   // mask=0 -> -inf -> weight 0
    tm_s[o] = make_float2(2.0f * kcoef * to, fmaf(-kcoef * to, to, lm));
  }

  const float tq = query_times[b * NQ + q0 + qi * 16 + row];
  const float Aq = -kcoef * tq * tq;

  f32x4_t acc[4];
  #pragma unroll
  for (int nt = 0; nt < 4; ++nt) acc[nt] = f32x4_t{0.f, 0.f, 0.f, 0.f};
  float wsum = 0.f;

  const short* EtB = Et + (size_t)b * ND * NO;

  // staging: thread owns 16B chunk c=tid of the [128 d][32 o] tile.
  // LDS slot (c&3) holds source o-slot s = (c&3)^(d&3)  (XOR swizzle, involution).
  const int sd = tid >> 2;
  const int ss = (tid & 3) ^ (sd & 3);
  const short* srcBase = EtB + (size_t)sd * NO + ss * 8;
  short* dst0 = Elds + tid * 8;              // buf0, lane-linear (gload_lds requirement)
  short* dst1 = Elds + 4096 + tid * 8;       // buf1

  // B-frag read offset (shorts): row-major d*64B, o-slot XOR'ed with (row&3)
  const int ldsRdOff = ((dh * 64 + row) << 5) + ((g ^ (row & 3)) << 3);

  // prologue: tile 0 -> buf0
  GLOAD_LDS16(srcBase + 0, dst0);
  __syncthreads();                           // tm + tile0 ready

#define COMPUTE_STEP(EB, ko)                                                        \
  {                                                                                 \
    const float4* tmf = reinterpret_cast<const float4*>(tm_s + (ko)) + g * 4;       \
    float4 p0 = tmf[0], p1 = tmf[1], p2 = tmf[2], p3 = tmf[3];                      \
    float w0 = fast_exp2(Aq + fmaf(p0.x, tq, p0.y));                                \
    float w1 = fast_exp2(Aq + fmaf(p0.z, tq, p0.w));                                \
    float w2 = fast_exp2(Aq + fmaf(p1.x, tq, p1.y));                                \
    float w3 = fast_exp2(Aq + fmaf(p1.z, tq, p1.w));                                \
    float w4 = fast_exp2(Aq + fmaf(p2.x, tq, p2.y));                                \
    float w5 = fast_exp2(Aq + fmaf(p2.z, tq, p2.w));                                \
    float w6 = fast_exp2(Aq + fmaf(p3.x, tq, p3.y));                                \
    float w7 = fast_exp2(Aq + fmaf(p3.z, tq, p3.w));                                \
    wsum += ((w0 + w1) + (w2 + w3)) + ((w4 + w5) + (w6 + w7));                      \
    union { bf16x8_t v; __hip_bfloat162 h[4]; } af;                                 \
    af.h[0] = __float22bfloat162_rn(make_float2(w0, w1));                           \
    af.h[1] = __float22bfloat162_rn(make_float2(w2, w3));                           \
    af.h[2] = __float22bfloat162_rn(make_float2(w4, w5));                           \
    af.h[3] = __float22bfloat162_rn(make_float2(w6, w7));                           \
    _Pragma("unroll")                                                               \
    for (int nt = 0; nt < 4; ++nt) {                                                \
      bf16x8_t bfrag = *reinterpret_cast<const bf16x8_t*>((EB) + ldsRdOff + nt * 512); \
      acc[nt] = __builtin_amdgcn_mfma_f32_16x16x32_bf16(af.v, bfrag, acc[nt], 0, 0, 0); \
    }                                                                               \
  }

  for (int kt2 = 0; kt2 < 32; ++kt2) {
    const int ko = kt2 * 64;
    // phase A: prefetch tile (2*kt2+1) -> buf1, compute buf0 (tile 2*kt2)
    GLOAD_LDS16(srcBase + ko + 32, dst1);
    COMPUTE_STEP(Elds, ko)
    __syncthreads();
    // phase B: prefetch tile (2*kt2+2) -> buf0 (if any), compute buf1
    if (kt2 < 31) GLOAD_LDS16(srcBase + ko + 64, dst0);
    COMPUTE_STEP(Elds + 4096, ko + 32)
    __syncthreads();
  }
#undef COMPUTE_STEP

  // full per-row weight sum (row = lane&15)
  wsum += __shfl_xor(wsum, 16);
  wsum += __shfl_xor(wsum, 32);

  // normalize + transpose into qe (bf16) for the projection GEMM
  #pragma unroll
  for (int r = 0; r < 4; ++r) {
    float ws  = __shfl(wsum, g * 4 + r);     // lanes 0..15 hold rows 0..15
    float inv = 1.0f / fmaxf(ws, 1e-8f);
    #pragma unroll
    for (int nt = 0; nt < 4; ++nt) {
      qe[(qi * 16 + g * 4 + r) * 136 + dh * 64 + nt * 16 + row] = f2bf(acc[nt][r] * inv);
    }
  }
  __syncthreads();

  // projection: out[q][e] = sum_d qe[q][d] * W[e][d] + b[e]
  f32x4_t pacc[4];
  #pragma unroll
  for (int nt = 0; nt < 4; ++nt) pacc[nt] = f32x4_t{0.f, 0.f, 0.f, 0.f};
  #pragma unroll
  for (int ks = 0; ks < 4; ++ks) {
    bf16x8_t aq = *reinterpret_cast<const bf16x8_t*>(
        qe + (qi * 16 + row) * 136 + ks * 32 + g * 8);
    #pragma unroll
    for (int nt = 0; nt < 4; ++nt) {
      bf16x8_t bw = *reinterpret_cast<const bf16x8_t*>(
          Wbf + (dh * 64 + nt * 16 + row) * 128 + ks * 32 + g * 8);
      pacc[nt] = __builtin_amdgcn_mfma_f32_16x16x32_bf16(aq, bw, pacc[nt], 0, 0, 0);
    }
  }
  #pragma unroll
  for (int nt = 0; nt < 4; ++nt) {
    int e = dh * 64 + nt * 16 + row;
    float bias = b_proj[e];
    #pragma unroll
    for (int r = 0; r < 4; ++r) {
      int q = q0 + qi * 16 + g * 4 + r;
      out[((size_t)(b * NQ + q)) * ND + e] = pacc[nt][r] + bias;
    }
  }
}

extern "C" void kernel_launch(void* const* d_in, const int* in_sizes, int n_in,
                              void* d_out, int out_size, void* d_ws, size_t ws_size,
                              hipStream_t stream) {
  const float* obs_emb     = (const float*)d_in[0];
  const float* obs_times   = (const float*)d_in[1];
  const float* query_times = (const float*)d_in[2];
  const float* obs_mask    = (const float*)d_in[3];
  const float* log_sigma   = (const float*)d_in[4];
  const float* W_proj      = (const float*)d_in[5];
  const float* b_proj      = (const float*)d_in[6];
  float* out = (float*)d_out;

  short* Et  = (short*)d_ws;                         // 8*128*2048 bf16 = 4 MB
  short* Wbf = Et + (size_t)NB * ND * NO;            // 128*128 bf16 = 32 KB

  prep_kernel<<<NB * (NO / 64) + 1, 256, 0, stream>>>(obs_emb, W_proj, Et, Wbf);
  agg_kernel<<<NB * (NQ / 64), 512, 0, stream>>>(obs_times, query_times, obs_mask,
                                                 log_sigma, Et, Wbf, b_proj, out);
}

// Round 3
// 34.941 us; speedup vs baseline: 1.5343x; 1.4652x over previous
//
#include <hip/hip_runtime.h>
#include <hip/hip_bf16.h>

typedef __attribute__((ext_vector_type(8))) short bf16x8_t;
typedef __attribute__((ext_vector_type(4))) float f32x4_t;

#define NB 8
#define NO 2048
#define NQ 2048
#define ND 128

__device__ __forceinline__ float fast_exp2(float x){
#if __has_builtin(__builtin_amdgcn_exp2f)
  return __builtin_amdgcn_exp2f(x);
#else
  return exp2f(x);
#endif
}

// round-to-nearest-even f32 -> bf16 bits (finite inputs only)
__device__ __forceinline__ short f2bf(float f){
  unsigned u = __float_as_uint(f);
  unsigned r = (u + 0x7fffu + ((u >> 16) & 1u)) >> 16;
  return (short)(unsigned short)r;
}

// ---------------- prep ----------------
// Etf: fragment-tiled B operand. Fragment (b, d16, k32) is 1KB contiguous:
//   lane l, j in 0..7  ->  element (d = d16*16 + (l&15), o = k32*32 + (l>>4)*8 + j)
// frag address (shorts): ((b*8 + d16)*64 + k32) * 512 + l*8
// Wbf: bf16(W_proj), row-major.
__global__ __launch_bounds__(256) void prep_kernel(
    const float* __restrict__ obs_emb, const float* __restrict__ W_proj,
    short* __restrict__ Etf, short* __restrict__ Wbf)
{
  const int blk = blockIdx.x;
  const int tid = threadIdx.x;
  if (blk < NB * (NO / 64)) {
    // transpose a 64o x 128d tile; tileT[d][o] swizzled: slot ^= (d>>1)&7
    __shared__ __align__(16) short tileT[128 * 64];   // 16 KB
    const int b  = blk >> 5;
    const int o0 = (blk & 31) * 64;
    #pragma unroll
    for (int i = 0; i < 8; ++i) {
      int c  = i * 256 + tid;                // 0..2047 float4-chunks of 64x128 tile
      int ol = c >> 5;                       // o 0..63
      int dc = c & 31;                       // d-quad 0..31
      union { float4 v4; float f[4]; } u;
      u.v4 = *reinterpret_cast<const float4*>(
          obs_emb + ((size_t)(b * NO + o0 + ol)) * ND + dc * 4);
      int j = ol >> 3, oin = ol & 7;         // 16B slot j (0..7), elem within
      #pragma unroll
      for (int q = 0; q < 4; ++q) {
        int d = dc * 4 + q;
        tileT[d * 64 + ((j ^ ((d >> 1) & 7)) << 3) + oin] = f2bf(u.f[q]);
      }
    }
    __syncthreads();
    // write out 16 fragments (d16 0..7, k32rel 0..1), coalesced 16B chunks
    const int k0 = o0 >> 5;
    #pragma unroll
    for (int u = 0; u < 4; ++u) {
      int c = tid * 4 + u;                   // 0..1023 chunk id
      int fragIdx = c >> 6;                  // 0..15
      int l       = c & 63;
      int d16     = fragIdx >> 1;
      int krel    = fragIdx & 1;
      int d       = d16 * 16 + (l & 15);
      int s       = krel * 4 + (l >> 4);     // nominal 16B slot in tileT row
      const int4 v = *reinterpret_cast<const int4*>(
          tileT + d * 64 + ((s ^ ((d >> 1) & 7)) << 3));
      *reinterpret_cast<int4*>(
          Etf + (((size_t)(b * 8 + d16)) * 64 + (k0 + krel)) * 512 + l * 8) = v;
    }
  } else {
    // W conversion: 128x128 f32 -> bf16, row-major unchanged
    #pragma unroll
    for (int i = 0; i < 16; ++i) {
      int idx = i * 256 + tid;               // float4 index 0..4095
      float4 v = reinterpret_cast<const float4*>(W_proj)[idx];
      union { int2 i2; __hip_bfloat162 h[2]; } u;
      u.h[0] = __float22bfloat162_rn(make_float2(v.x, v.y));
      u.h[1] = __float22bfloat162_rn(make_float2(v.z, v.w));
      reinterpret_cast<int2*>(Wbf)[idx] = u.i2;
    }
  }
}

// ---------------- main fused kernel ----------------
// grid: 256 blocks = 8 batches x 32 q-tiles(64 rows); b = blockIdx&7 (XCD-aligned).
// 512 thr = 8 waves: qi = wave&3 (16 q rows), dh = wave>>2 (64 d cols).
// K-loop: barrier-free; B-frags streamed coalesced from L1/L2, 2-stage pipeline.
__global__ __launch_bounds__(512, 2) void agg_kernel(
    const float* __restrict__ obs_times, const float* __restrict__ query_times,
    const float* __restrict__ obs_mask, const float* __restrict__ log_sigma,
    const short* __restrict__ Etf, const short* __restrict__ Wbf,
    const float* __restrict__ b_proj, float* __restrict__ out)
{
  __shared__ __align__(16) char smem[64 * 136 * 2];   // tm (16KB) overlaid by qe[64][136]
  float2* tm_s = reinterpret_cast<float2*>(smem);
  short*  qe   = reinterpret_cast<short*>(smem);

  const int tid  = threadIdx.x;
  const int lane = tid & 63;
  const int wave = tid >> 6;
  const int qi  = wave & 3;
  const int dh  = wave >> 2;
  const int row = lane & 15;
  const int g   = lane >> 4;

  const int b  = blockIdx.x & 7;             // XCD-aligned batch
  const int q0 = (blockIdx.x >> 3) * 64;

  const float ls    = log_sigma[0];
  const float kcoef = 0.72134752f * __expf(-2.0f * ls);  // 0.5*log2(e)/sigma^2

  // stage per-o weight coefficients: arg = Aq + Co*tq + Bo'; Bo' folds log2(mask)
  for (int o = tid; o < NO; o += 512) {
    float to = obs_times[b * NO + o];
    float m  = obs_mask[b * NO + o];
    float lm = __log2f(m);                   // mask=0 -> -inf -> weight 0
    tm_s[o] = make_float2(2.0f * kcoef * to, fmaf(-kcoef * to, to, lm));
  }

  const float tq = query_times[b * NQ + q0 + qi * 16 + row];
  const float Aq = -kcoef * tq * tq;

  f32x4_t acc[4];
  #pragma unroll
  for (int nt = 0; nt < 4; ++nt) acc[nt] = f32x4_t{0.f, 0.f, 0.f, 0.f};
  float wsum = 0.f;

  // per-wave fragment stream base: d16 = dh*4 + nt, frag k advances 512 shorts
  const short* fw = Etf + ((size_t)b * 8 + dh * 4) * 64 * 512 + lane * 8;

  __syncthreads();                           // tm ready

#define LOADF(dst, ks)                                                              \
  _Pragma("unroll")                                                                 \
  for (int nt = 0; nt < 4; ++nt)                                                    \
    dst[nt] = *reinterpret_cast<const bf16x8_t*>(fw + nt * 32768 + (ks) * 512);

#define WSTEP(frg, ks)                                                              \
  {                                                                                 \
    const float4* tmf = reinterpret_cast<const float4*>(tm_s + (ks) * 32) + g * 4;  \
    float4 p0 = tmf[0], p1 = tmf[1], p2 = tmf[2], p3 = tmf[3];                      \
    float w0 = fast_exp2(Aq + fmaf(p0.x, tq, p0.y));                                \
    float w1 = fast_exp2(Aq + fmaf(p0.z, tq, p0.w));                                \
    float w2 = fast_exp2(Aq + fmaf(p1.x, tq, p1.y));                                \
    float w3 = fast_exp2(Aq + fmaf(p1.z, tq, p1.w));                                \
    float w4 = fast_exp2(Aq + fmaf(p2.x, tq, p2.y));                                \
    float w5 = fast_exp2(Aq + fmaf(p2.z, tq, p2.w));                                \
    float w6 = fast_exp2(Aq + fmaf(p3.x, tq, p3.y));                                \
    float w7 = fast_exp2(Aq + fmaf(p3.z, tq, p3.w));                                \
    wsum += ((w0 + w1) + (w2 + w3)) + ((w4 + w5) + (w6 + w7));                      \
    union { bf16x8_t v; __hip_bfloat162 h[4]; } af;                                 \
    af.h[0] = __float22bfloat162_rn(make_float2(w0, w1));                           \
    af.h[1] = __float22bfloat162_rn(make_float2(w2, w3));                           \
    af.h[2] = __float22bfloat162_rn(make_float2(w4, w5));                           \
    af.h[3] = __float22bfloat162_rn(make_float2(w6, w7));                           \
    _Pragma("unroll")                                                               \
    for (int nt = 0; nt < 4; ++nt)                                                  \
      acc[nt] = __builtin_amdgcn_mfma_f32_16x16x32_bf16(af.v, frg[nt], acc[nt], 0, 0, 0); \
  }

  bf16x8_t bA[4], bB[4];
  LOADF(bA, 0)
  for (int ks = 0; ks < 64; ks += 2) {
    LOADF(bB, ks + 1)
    WSTEP(bA, ks)
    if (ks + 2 < 64) LOADF(bA, ks + 2)
    WSTEP(bB, ks + 1)
  }
#undef LOADF
#undef WSTEP

  // full per-row weight sum (row = lane&15)
  wsum += __shfl_xor(wsum, 16);
  wsum += __shfl_xor(wsum, 32);

  __syncthreads();                           // K-loop done everywhere; tm dead -> qe overlay

  // normalize + transpose into qe (bf16) for the projection GEMM
  #pragma unroll
  for (int r = 0; r < 4; ++r) {
    float ws  = __shfl(wsum, g * 4 + r);     // lanes 0..15 hold rows 0..15
    float inv = 1.0f / fmaxf(ws, 1e-8f);
    #pragma unroll
    for (int nt = 0; nt < 4; ++nt) {
      qe[(qi * 16 + g * 4 + r) * 136 + dh * 64 + nt * 16 + row] = f2bf(acc[nt][r] * inv);
    }
  }
  __syncthreads();

  // projection: out[q][e] = sum_d qe[q][d] * W[e][d] + b[e]
  f32x4_t pacc[4];
  #pragma unroll
  for (int nt = 0; nt < 4; ++nt) pacc[nt] = f32x4_t{0.f, 0.f, 0.f, 0.f};
  #pragma unroll
  for (int ks = 0; ks < 4; ++ks) {
    bf16x8_t aq = *reinterpret_cast<const bf16x8_t*>(
        qe + (qi * 16 + row) * 136 + ks * 32 + g * 8);
    #pragma unroll
    for (int nt = 0; nt < 4; ++nt) {
      bf16x8_t bw = *reinterpret_cast<const bf16x8_t*>(
          Wbf + (dh * 64 + nt * 16 + row) * 128 + ks * 32 + g * 8);
      pacc[nt] = __builtin_amdgcn_mfma_f32_16x16x32_bf16(aq, bw, pacc[nt], 0, 0, 0);
    }
  }
  #pragma unroll
  for (int nt = 0; nt < 4; ++nt) {
    int e = dh * 64 + nt * 16 + row;
    float bias = b_proj[e];
    #pragma unroll
    for (int r = 0; r < 4; ++r) {
      int q = q0 + qi * 16 + g * 4 + r;
      out[((size_t)(b * NQ + q)) * ND + e] = pacc[nt][r] + bias;
    }
  }
}

extern "C" void kernel_launch(void* const* d_in, const int* in_sizes, int n_in,
                              void* d_out, int out_size, void* d_ws, size_t ws_size,
                              hipStream_t stream) {
  const float* obs_emb     = (const float*)d_in[0];
  const float* obs_times   = (const float*)d_in[1];
  const float* query_times = (const float*)d_in[2];
  const float* obs_mask    = (const float*)d_in[3];
  const float* log_sigma   = (const float*)d_in[4];
  const float* W_proj      = (const float*)d_in[5];
  const float* b_proj      = (const float*)d_in[6];
  float* out = (float*)d_out;

  short* Etf = (short*)d_ws;                         // 8*128*2048 bf16 = 4 MB (frag-tiled)
  short* Wbf = Etf + (size_t)NB * ND * NO;           // 128*128 bf16 = 32 KB

  prep_kernel<<<NB * (NO / 64) + 1, 256, 0, stream>>>(obs_emb, W_proj, Etf, Wbf);
  agg_kernel<<<NB * (NQ / 64), 512, 0, stream>>>(obs_times, query_times, obs_mask,
                                                 log_sigma, Etf, Wbf, b_proj, out);
}